// Round 7
// baseline (100.149 us; speedup 1.0000x reference)
//
#include <hip/hip_runtime.h>

#define NMODE 8
#define NPSI  512

// 2 independent particles per thread (i, i+N/2); 256 threads/block; 1024 blocks.
// No LDS: tables (18KB) are L1/L2-resident, taps gathered from global.
// Per-mode constants on the scalar (SGPR) path, shared by both particles.
// Branch trig via rotation identity. Goal: 2x per-thread ILP to overlap the
// per-wave latency chains (SMEM rounds, gather->interp deps, trans chains).
__global__ __launch_bounds__(256) void eik_kernel(
    const float* __restrict__ t_p,
    const float* __restrict__ r_p,
    const float* __restrict__ vp_p,
    const float* __restrict__ z_p,
    const float* __restrict__ psi_p,
    const float* __restrict__ ghre_p,
    const float* __restrict__ ghim_p,
    const float* __restrict__ a0tab_p,
    const float* __restrict__ iotatab_p,
    const float* __restrict__ psi0_p,
    const float* __restrict__ psisc_p,
    const float* __restrict__ alsc_p,
    const float* __restrict__ omega_p,
    const int*   __restrict__ nmode_p,
    float* __restrict__ out,
    int npart)
{
    constexpr float R0      = 1.7f;
    constexpr float TWO_PI  = 6.28318530717958647692f;
    constexpr float INV_2PI = 0.15915494309189533577f;
    constexpr float NHL2E   = -0.72134752044448170368f; // -0.5*log2(e)

    const int half = npart >> 1;
    const int i0 = blockIdx.x * 256 + threadIdx.x;
    if (i0 >= half) return;
    const int i1 = i0 + half;

    const float tval = t_p[0];

    // ---- particle inputs (coalesced), both streams issued together ----
    const float psA = psi_p[i0], psB = psi_p[i1];
    const float rrA = r_p[i0],   rrB = r_p[i1];
    const float zzA = z_p[i0],   zzB = z_p[i1];
    const float vpA = vp_p[i0],  vpB = vp_p[i1];

    const float thA = atan2f(zzA, rrA - R0);
    const float thB = atan2f(zzB, rrB - R0);

    // ---- Catmull-Rom setup, per stream ----
    const float sA = psA * (float)(NPSI - 1);
    int iiA = (int)floorf(sA);
    iiA = iiA < 1 ? 1 : (iiA > NPSI - 3 ? NPSI - 3 : iiA);
    const float ttA = sA - (float)iiA;
    const float tA2 = ttA * ttA, tA3 = tA2 * ttA;
    const float wA0 = 0.5f * (-tA3 + 2.0f * tA2 - ttA);
    const float wA1 = 0.5f * (3.0f * tA3 - 5.0f * tA2 + 2.0f);
    const float wA2 = 0.5f * (-3.0f * tA3 + 4.0f * tA2 + ttA);
    const float wA3 = 0.5f * (tA3 - tA2);

    const float sB = psB * (float)(NPSI - 1);
    int iiB = (int)floorf(sB);
    iiB = iiB < 1 ? 1 : (iiB > NPSI - 3 ? NPSI - 3 : iiB);
    const float ttB = sB - (float)iiB;
    const float tB2 = ttB * ttB, tB3 = tB2 * ttB;
    const float wB0 = 0.5f * (-tB3 + 2.0f * tB2 - ttB);
    const float wB1 = 0.5f * (3.0f * tB3 - 5.0f * tB2 + 2.0f);
    const float wB2 = 0.5f * (-3.0f * tB3 + 4.0f * tB2 + ttB);
    const float wB3 = 0.5f * (tB3 - tB2);

    // ---- gather tap rows for both streams (8 x float4 + 8 scalars) ----
    const float4* a0q = reinterpret_cast<const float4*>(a0tab_p);
    const int rA = iiA - 1, rB = iiB - 1;
    const float4 Alo0 = a0q[2*(rA+0)+0], Ahi0 = a0q[2*(rA+0)+1];
    const float4 Alo1 = a0q[2*(rA+1)+0], Ahi1 = a0q[2*(rA+1)+1];
    const float4 Alo2 = a0q[2*(rA+2)+0], Ahi2 = a0q[2*(rA+2)+1];
    const float4 Alo3 = a0q[2*(rA+3)+0], Ahi3 = a0q[2*(rA+3)+1];
    const float4 Blo0 = a0q[2*(rB+0)+0], Bhi0 = a0q[2*(rB+0)+1];
    const float4 Blo1 = a0q[2*(rB+1)+0], Bhi1 = a0q[2*(rB+1)+1];
    const float4 Blo2 = a0q[2*(rB+2)+0], Bhi2 = a0q[2*(rB+2)+1];
    const float4 Blo3 = a0q[2*(rB+3)+0], Bhi3 = a0q[2*(rB+3)+1];
    const float ioA0 = iotatab_p[rA+0], ioA1 = iotatab_p[rA+1];
    const float ioA2 = iotatab_p[rA+2], ioA3 = iotatab_p[rA+3];
    const float ioB0 = iotatab_p[rB+0], ioB1 = iotatab_p[rB+1];
    const float ioB2 = iotatab_p[rB+2], ioB3 = iotatab_p[rB+3];

    float a0A[NMODE], a0B[NMODE];
    a0A[0] = wA0*Alo0.x + wA1*Alo1.x + wA2*Alo2.x + wA3*Alo3.x;
    a0A[1] = wA0*Alo0.y + wA1*Alo1.y + wA2*Alo2.y + wA3*Alo3.y;
    a0A[2] = wA0*Alo0.z + wA1*Alo1.z + wA2*Alo2.z + wA3*Alo3.z;
    a0A[3] = wA0*Alo0.w + wA1*Alo1.w + wA2*Alo2.w + wA3*Alo3.w;
    a0A[4] = wA0*Ahi0.x + wA1*Ahi1.x + wA2*Ahi2.x + wA3*Ahi3.x;
    a0A[5] = wA0*Ahi0.y + wA1*Ahi1.y + wA2*Ahi2.y + wA3*Ahi3.y;
    a0A[6] = wA0*Ahi0.z + wA1*Ahi1.z + wA2*Ahi2.z + wA3*Ahi3.z;
    a0A[7] = wA0*Ahi0.w + wA1*Ahi1.w + wA2*Ahi2.w + wA3*Ahi3.w;
    const float ioA = wA0*ioA0 + wA1*ioA1 + wA2*ioA2 + wA3*ioA3;
    a0B[0] = wB0*Blo0.x + wB1*Blo1.x + wB2*Blo2.x + wB3*Blo3.x;
    a0B[1] = wB0*Blo0.y + wB1*Blo1.y + wB2*Blo2.y + wB3*Blo3.y;
    a0B[2] = wB0*Blo0.z + wB1*Blo1.z + wB2*Blo2.z + wB3*Blo3.z;
    a0B[3] = wB0*Blo0.w + wB1*Blo1.w + wB2*Blo2.w + wB3*Blo3.w;
    a0B[4] = wB0*Bhi0.x + wB1*Bhi1.x + wB2*Bhi2.x + wB3*Bhi3.x;
    a0B[5] = wB0*Bhi0.y + wB1*Bhi1.y + wB2*Bhi2.y + wB3*Bhi3.y;
    a0B[6] = wB0*Bhi0.z + wB1*Bhi1.z + wB2*Bhi2.z + wB3*Bhi3.z;
    a0B[7] = wB0*Bhi0.w + wB1*Bhi1.w + wB2*Bhi2.w + wB3*Bhi3.w;
    const float ioB = wB0*ioB0 + wB1*ioB1 + wB2*ioB2 + wB3*ioB3;

    const float atA = ioA * thA, dybA = ioA * TWO_PI;
    const float atB = ioB * thB, dybB = ioB * TWO_PI;

    float acc0aA = 0.f, acc0bA = 0.f, acc1aA = 0.f, acc1bA = 0.f;
    float acc0aB = 0.f, acc0bB = 0.f, acc1aB = 0.f, acc1bB = 0.f;

    #pragma unroll
    for (int m = 0; m < NMODE; ++m) {
        // ---- wave-uniform constants (SGPR), shared by both streams ----
        const float c0r0 = ghre_p[m*12+ 0], c0r1 = ghre_p[m*12+ 1];
        const float c1r0 = ghre_p[m*12+ 2], c1r1 = ghre_p[m*12+ 3];
        const float c2r0 = ghre_p[m*12+ 4], c2r1 = ghre_p[m*12+ 5];
        const float c3r0 = ghre_p[m*12+ 6], c3r1 = ghre_p[m*12+ 7];
        const float c4r0 = ghre_p[m*12+ 8], c4r1 = ghre_p[m*12+ 9];
        const float c5r0 = ghre_p[m*12+10], c5r1 = ghre_p[m*12+11];
        const float c0i0 = ghim_p[m*12+ 0], c0i1 = ghim_p[m*12+ 1];
        const float c1i0 = ghim_p[m*12+ 2], c1i1 = ghim_p[m*12+ 3];
        const float c2i0 = ghim_p[m*12+ 4], c2i1 = ghim_p[m*12+ 5];
        const float c3i0 = ghim_p[m*12+ 6], c3i1 = ghim_p[m*12+ 7];
        const float c4i0 = ghim_p[m*12+ 8], c4i1 = ghim_p[m*12+ 9];
        const float c5i0 = ghim_p[m*12+10], c5i1 = ghim_p[m*12+11];
        const float psi0m = psi0_p[m];
        const float ipsc  = __builtin_amdgcn_rcpf(psisc_p[m]);
        const float iasc  = __builtin_amdgcn_rcpf(alsc_p[m]);
        const float ot    = omega_p[m] * tval;
        const float nf    = (float)nmode_p[m];

        #pragma unroll
        for (int pp = 0; pp < 2; ++pp) {   // two independent particle streams
            const float ps  = pp ? psB : psA;
            const float vp  = pp ? vpB : vpA;
            const float at  = pp ? atB : atA;
            const float dyb = pp ? dybB : dybA;
            const float iov = pp ? ioB : ioA;
            const float a0  = pp ? a0B[m] : a0A[m];

            const float x     = (ps - psi0m) * ipsc;
            const float xx    = x * x;
            const float h20   = fmaf(4.0f, xx, -2.0f);
            const float xterm = xx * NHL2E;
            const float base  = at - a0;
            const float y1    = base * iasc;
            const float dy    = dyb * iasc;
            const float pcr   = (ot - nf * (vp - base)) * INV_2PI;
            const float dpr   = nf * iov;

            const float snC = __builtin_amdgcn_sinf(__builtin_amdgcn_fractf(pcr));
            const float csC = __builtin_amdgcn_cosf(__builtin_amdgcn_fractf(pcr));
            const float snD = __builtin_amdgcn_sinf(__builtin_amdgcn_fractf(dpr));
            const float csD = __builtin_amdgcn_cosf(__builtin_amdgcn_fractf(dpr));
            const float pcc = csC * csD, pss = snC * snD;
            const float psc_ = snC * csD, pcs = csC * snD;
            const float csM = pcc + pss, snM = psc_ - pcs;
            const float csP = pcc - pss, snP = psc_ + pcs;

            const float pxr0 = fmaf(c3r0, h20, fmaf(c1r0, x, c0r0));
            const float pxr1 = fmaf(c3r1, h20, fmaf(c1r1, x, c0r1));
            const float pxi0 = fmaf(c3i0, h20, fmaf(c1i0, x, c0i0));
            const float pxi1 = fmaf(c3i1, h20, fmaf(c1i1, x, c0i1));
            const float er0  = fmaf(c4r0, x, c2r0);
            const float er1  = fmaf(c4r1, x, c2r1);
            const float ei0  = fmaf(c4i0, x, c2i0);
            const float ei1  = fmaf(c4i1, x, c2i1);

            float s0a = 0.f, s0b = 0.f, s1a = 0.f, s1b = 0.f;
            #pragma unroll
            for (int k = 0; k < 3; ++k) {
                const float kf = (float)(k - 1);
                const float y  = fmaf(kf, dy, y1);
                const float cs = (k == 0) ? csM : (k == 1) ? csC : csP;
                const float sn = (k == 0) ? snM : (k == 1) ? snC : snP;
                const float yy  = y * y;
                const float g   = __builtin_amdgcn_exp2f(fmaf(yy, NHL2E, xterm));
                const float h02 = fmaf(4.0f, yy, -2.0f);
                const float pr0 = fmaf(c5r0, h02, fmaf(er0, y, pxr0));
                const float pr1 = fmaf(c5r1, h02, fmaf(er1, y, pxr1));
                const float pi0 = fmaf(c5i0, h02, fmaf(ei0, y, pxi0));
                const float pi1 = fmaf(c5i1, h02, fmaf(ei1, y, pxi1));
                const float gc = g * cs;
                const float gs = g * sn;
                s0a = fmaf(pr0, gc, s0a);
                s0b = fmaf(pi0, gs, s0b);
                s1a = fmaf(pr1, gc, s1a);
                s1b = fmaf(pi1, gs, s1b);
            }
            if (pp == 0) {
                acc0aA += s0a; acc0bA += s0b; acc1aA += s1a; acc1bA += s1b;
            } else {
                acc0aB += s0a; acc0bB += s0b; acc1aB += s1a; acc1bB += s1b;
            }
        }
    }

    reinterpret_cast<float2*>(out)[i0] = make_float2(acc0aA - acc0bA, acc1aA - acc1bA);
    reinterpret_cast<float2*>(out)[i1] = make_float2(acc0aB - acc0bB, acc1aB - acc1bB);
}

extern "C" void kernel_launch(void* const* d_in, const int* in_sizes, int n_in,
                              void* d_out, int out_size, void* d_ws, size_t ws_size,
                              hipStream_t stream) {
    const float* t      = (const float*)d_in[0];
    const float* r      = (const float*)d_in[1];
    const float* varphi = (const float*)d_in[2];
    const float* z      = (const float*)d_in[3];
    const float* psi    = (const float*)d_in[4];
    const float* gh_re  = (const float*)d_in[5];
    const float* gh_im  = (const float*)d_in[6];
    const float* a0t    = (const float*)d_in[7];
    const float* iot    = (const float*)d_in[8];
    const float* psi0   = (const float*)d_in[9];
    const float* psc    = (const float*)d_in[10];
    const float* asc    = (const float*)d_in[11];
    const float* omg    = (const float*)d_in[12];
    const int*   nn     = (const int*)d_in[13];
    float* out = (float*)d_out;

    const int npart = in_sizes[1];
    const int half  = npart >> 1;
    const int blocks = (half + 255) / 256;
    eik_kernel<<<blocks, 256, 0, stream>>>(t, r, varphi, z, psi, gh_re, gh_im,
                                           a0t, iot, psi0, psc, asc, omg, nn,
                                           out, npart);
}

// Round 8
// 99.370 us; speedup vs baseline: 1.0078x; 1.0078x over previous
//
#include <hip/hip_runtime.h>

#define NMODE 8
#define NPSI  512
#define REP   2   // DIAGNOSTIC: run the computation twice (laundered inputs, no CSE)
                  // so eik_kernel exceeds the ~44us fill dispatches and shows up in
                  // the top-5 rocprof rows with full counters. Output is identical
                  // (both passes compute the same values). Revert to 1 next round.

// 1 particle per thread; 256 threads/block; 2048 blocks. No LDS: tables
// (16KB+2KB) are L1/L2-resident, taps gathered from global. Per-mode
// constants on the scalar (SGPR) path. Branch trig via rotation identity.
__global__ __launch_bounds__(256) void eik_kernel(
    const float* __restrict__ t_p,
    const float* __restrict__ r_p,
    const float* __restrict__ vp_p,
    const float* __restrict__ z_p,
    const float* __restrict__ psi_p,
    const float* __restrict__ ghre_p,
    const float* __restrict__ ghim_p,
    const float* __restrict__ a0tab_p,
    const float* __restrict__ iotatab_p,
    const float* __restrict__ psi0_p,
    const float* __restrict__ psisc_p,
    const float* __restrict__ alsc_p,
    const float* __restrict__ omega_p,
    const int*   __restrict__ nmode_p,
    float* __restrict__ out,
    int npart)
{
    constexpr float R0      = 1.7f;
    constexpr float TWO_PI  = 6.28318530717958647692f;
    constexpr float INV_2PI = 0.15915494309189533577f;
    constexpr float NHL2E   = -0.72134752044448170368f; // -0.5*log2(e)

    const int i = blockIdx.x * 256 + threadIdx.x;
    if (i >= npart) return;

    // ---- particle inputs (coalesced), loaded once ----
    const float ps_in = psi_p[i];
    const float rr_in = r_p[i];
    const float zz_in = z_p[i];
    const float vp_in = vp_p[i];
    const float tval  = t_p[0];

    float o0 = 0.0f, o1 = 0.0f;

    #pragma unroll 1
    for (int rep = 0; rep < REP; ++rep) {
        // Launder inputs: formally-new SSA values each pass -> the compiler
        // cannot CSE pass 2 against pass 1; math (and result) is identical.
        float ps = ps_in, rr = rr_in, zz = zz_in, vp = vp_in;
        asm volatile("" : "+v"(ps), "+v"(rr), "+v"(zz), "+v"(vp));

        const float th = atan2f(zz, rr - R0);

        // ---- Catmull-Rom setup (uniform grid over [0,1], 512 pts) ----
        const float s = ps * (float)(NPSI - 1);
        int ii = (int)floorf(s);
        ii = ii < 1 ? 1 : (ii > NPSI - 3 ? NPSI - 3 : ii);
        const float tt = s - (float)ii;
        const float t2 = tt * tt, t3 = t2 * tt;
        const float w0 = 0.5f * (-t3 + 2.0f * t2 - tt);
        const float w1 = 0.5f * (3.0f * t3 - 5.0f * t2 + 2.0f);
        const float w2 = 0.5f * (-3.0f * t3 + 4.0f * t2 + tt);
        const float w3 = 0.5f * (t3 - t2);

        // ---- gather all 4 tap rows from global (L1-resident tables) ----
        const float4* a0q = reinterpret_cast<const float4*>(a0tab_p);
        const int r0 = ii - 1;
        const float4 lo0 = a0q[2*(r0+0)+0], hi0 = a0q[2*(r0+0)+1];
        const float4 lo1 = a0q[2*(r0+1)+0], hi1 = a0q[2*(r0+1)+1];
        const float4 lo2 = a0q[2*(r0+2)+0], hi2 = a0q[2*(r0+2)+1];
        const float4 lo3 = a0q[2*(r0+3)+0], hi3 = a0q[2*(r0+3)+1];
        const float io0 = iotatab_p[r0+0], io1 = iotatab_p[r0+1];
        const float io2 = iotatab_p[r0+2], io3 = iotatab_p[r0+3];

        float a0v[NMODE];
        a0v[0] = w0*lo0.x + w1*lo1.x + w2*lo2.x + w3*lo3.x;
        a0v[1] = w0*lo0.y + w1*lo1.y + w2*lo2.y + w3*lo3.y;
        a0v[2] = w0*lo0.z + w1*lo1.z + w2*lo2.z + w3*lo3.z;
        a0v[3] = w0*lo0.w + w1*lo1.w + w2*lo2.w + w3*lo3.w;
        a0v[4] = w0*hi0.x + w1*hi1.x + w2*hi2.x + w3*hi3.x;
        a0v[5] = w0*hi0.y + w1*hi1.y + w2*hi2.y + w3*hi3.y;
        a0v[6] = w0*hi0.z + w1*hi1.z + w2*hi2.z + w3*hi3.z;
        a0v[7] = w0*hi0.w + w1*hi1.w + w2*hi2.w + w3*hi3.w;
        const float iotv = w0*io0 + w1*io1 + w2*io2 + w3*io3;

        const float at  = iotv * th;
        const float dyb = iotv * TWO_PI;

        float acc0a = 0.0f, acc0b = 0.0f;
        float acc1a = 0.0f, acc1b = 0.0f;

        #pragma unroll
        for (int m = 0; m < NMODE; ++m) {
            const float c0r0 = ghre_p[m*12+ 0], c0r1 = ghre_p[m*12+ 1];
            const float c1r0 = ghre_p[m*12+ 2], c1r1 = ghre_p[m*12+ 3];
            const float c2r0 = ghre_p[m*12+ 4], c2r1 = ghre_p[m*12+ 5];
            const float c3r0 = ghre_p[m*12+ 6], c3r1 = ghre_p[m*12+ 7];
            const float c4r0 = ghre_p[m*12+ 8], c4r1 = ghre_p[m*12+ 9];
            const float c5r0 = ghre_p[m*12+10], c5r1 = ghre_p[m*12+11];
            const float c0i0 = ghim_p[m*12+ 0], c0i1 = ghim_p[m*12+ 1];
            const float c1i0 = ghim_p[m*12+ 2], c1i1 = ghim_p[m*12+ 3];
            const float c2i0 = ghim_p[m*12+ 4], c2i1 = ghim_p[m*12+ 5];
            const float c3i0 = ghim_p[m*12+ 6], c3i1 = ghim_p[m*12+ 7];
            const float c4i0 = ghim_p[m*12+ 8], c4i1 = ghim_p[m*12+ 9];
            const float c5i0 = ghim_p[m*12+10], c5i1 = ghim_p[m*12+11];
            const float psi0m = psi0_p[m];
            const float ipsc  = __builtin_amdgcn_rcpf(psisc_p[m]);
            const float iasc  = __builtin_amdgcn_rcpf(alsc_p[m]);
            const float ot    = omega_p[m] * tval;
            const float nf    = (float)nmode_p[m];

            const float a0    = a0v[m];
            const float x     = (ps - psi0m) * ipsc;
            const float xx    = x * x;
            const float h20   = fmaf(4.0f, xx, -2.0f);
            const float xterm = xx * NHL2E;
            const float base  = at - a0;
            const float y1    = base * iasc;
            const float dy    = dyb * iasc;
            const float pcr   = (ot - nf * (vp - base)) * INV_2PI;
            const float dpr   = nf * iotv;

            const float snC = __builtin_amdgcn_sinf(__builtin_amdgcn_fractf(pcr));
            const float csC = __builtin_amdgcn_cosf(__builtin_amdgcn_fractf(pcr));
            const float snD = __builtin_amdgcn_sinf(__builtin_amdgcn_fractf(dpr));
            const float csD = __builtin_amdgcn_cosf(__builtin_amdgcn_fractf(dpr));
            const float pcc = csC * csD, pss = snC * snD;
            const float psc_ = snC * csD, pcs = csC * snD;
            const float csM = pcc + pss, snM = psc_ - pcs;
            const float csP = pcc - pss, snP = psc_ + pcs;

            const float pxr0 = fmaf(c3r0, h20, fmaf(c1r0, x, c0r0));
            const float pxr1 = fmaf(c3r1, h20, fmaf(c1r1, x, c0r1));
            const float pxi0 = fmaf(c3i0, h20, fmaf(c1i0, x, c0i0));
            const float pxi1 = fmaf(c3i1, h20, fmaf(c1i1, x, c0i1));
            const float er0  = fmaf(c4r0, x, c2r0);
            const float er1  = fmaf(c4r1, x, c2r1);
            const float ei0  = fmaf(c4i0, x, c2i0);
            const float ei1  = fmaf(c4i1, x, c2i1);

            #pragma unroll
            for (int k = 0; k < 3; ++k) {
                const float kf = (float)(k - 1);
                const float y  = fmaf(kf, dy, y1);
                const float cs = (k == 0) ? csM : (k == 1) ? csC : csP;
                const float sn = (k == 0) ? snM : (k == 1) ? snC : snP;
                const float yy  = y * y;
                const float g   = __builtin_amdgcn_exp2f(fmaf(yy, NHL2E, xterm));
                const float h02 = fmaf(4.0f, yy, -2.0f);
                const float pr0 = fmaf(c5r0, h02, fmaf(er0, y, pxr0));
                const float pr1 = fmaf(c5r1, h02, fmaf(er1, y, pxr1));
                const float pi0 = fmaf(c5i0, h02, fmaf(ei0, y, pxi0));
                const float pi1 = fmaf(c5i1, h02, fmaf(ei1, y, pxi1));
                const float gc = g * cs;
                const float gs = g * sn;
                acc0a = fmaf(pr0, gc, acc0a);
                acc0b = fmaf(pi0, gs, acc0b);
                acc1a = fmaf(pr1, gc, acc1a);
                acc1b = fmaf(pi1, gs, acc1b);
            }
        }

        o0 = acc0a - acc0b;
        o1 = acc1a - acc1b;
    }

    reinterpret_cast<float2*>(out)[i] = make_float2(o0, o1);
}

extern "C" void kernel_launch(void* const* d_in, const int* in_sizes, int n_in,
                              void* d_out, int out_size, void* d_ws, size_t ws_size,
                              hipStream_t stream) {
    const float* t      = (const float*)d_in[0];
    const float* r      = (const float*)d_in[1];
    const float* varphi = (const float*)d_in[2];
    const float* z      = (const float*)d_in[3];
    const float* psi    = (const float*)d_in[4];
    const float* gh_re  = (const float*)d_in[5];
    const float* gh_im  = (const float*)d_in[6];
    const float* a0t    = (const float*)d_in[7];
    const float* iot    = (const float*)d_in[8];
    const float* psi0   = (const float*)d_in[9];
    const float* psc    = (const float*)d_in[10];
    const float* asc    = (const float*)d_in[11];
    const float* omg    = (const float*)d_in[12];
    const int*   nn     = (const int*)d_in[13];
    float* out = (float*)d_out;

    const int npart  = in_sizes[1];
    const int blocks = (npart + 255) / 256;
    eik_kernel<<<blocks, 256, 0, stream>>>(t, r, varphi, z, psi, gh_re, gh_im,
                                           a0t, iot, psi0, psc, asc, omg, nn,
                                           out, npart);
}